// Round 2
// baseline (167.347 us; speedup 1.0000x reference)
//
#include <hip/hip_runtime.h>
#include <hip/hip_bf16.h>

// GQA paged-prefill attention, MI355X gfx950.
// Causal mask j<=i over concat(past,new) => only first Q_LEN (=1024) gathered
// past tokens are live. Flash-attention over tokens 0..1023 of paged cache.
//
// R2: reg-prefetch of next K/V tile (T14), block_table staged in LDS,
// coalesced K gather with ds_write_b128, qt-descending block order,
// SCALE folded into Q fragments.

#define NUM_HEADS 32
#define HEAD_DIM 128
#define Q_STRIDE 4096
#define SCALE 0.08838834764831845f

typedef short short8 __attribute__((ext_vector_type(8)));
typedef float f32x4 __attribute__((ext_vector_type(4)));
typedef unsigned short ushort_t;
typedef unsigned int uint_t;

__device__ __forceinline__ ushort_t f2bf(float f) {
    uint_t u = __builtin_bit_cast(uint_t, f);
    u += 0x7FFFu + ((u >> 16) & 1u);   // RNE
    return (ushort_t)(u >> 16);
}
__device__ __forceinline__ uint_t pk2(float a, float b) {
    return (uint_t)f2bf(a) | ((uint_t)f2bf(b) << 16);
}

__launch_bounds__(256, 3)
__global__ void attn_paged_prefill(const float* __restrict__ q,
                                   const float* __restrict__ kvc,
                                   const int* __restrict__ bt,
                                   float* __restrict__ out)
{
    __shared__ __align__(16) char sK[64 * 256];   // [tok][dim] bf16, swizzled
    __shared__ __align__(16) char sV[128 * 128];  // [dim][tok] bf16, swizzled
    __shared__ __align__(16) char sP[4][2048];
    __shared__ int sPages[64];                    // pages for tokens 0..1023

    const int bid = blockIdx.x;
    const int h   = bid & 31;
    const int qt  = 15 - (bid >> 5);   // long blocks first
    const int hkv = h >> 2;
    const int tid  = threadIdx.x;
    const int w    = tid >> 6;
    const int lane = tid & 63;
    const int l15  = lane & 15;
    const int lhi  = lane >> 4;

    if (tid < 64) sPages[tid] = bt[tid];

    // ---- Q fragments (SCALE folded): wave w owns rows qt*64 + w*16 + l15
    short8 qf[4];
    {
        const int qrow = qt * 64 + w * 16 + l15;
        const float* qp = q + (size_t)qrow * Q_STRIDE + h * HEAD_DIM;
#pragma unroll
        for (int s = 0; s < 4; ++s) {
            const int d0 = s * 32 + lhi * 8;
            float4 a = *(const float4*)(qp + d0);
            float4 b = *(const float4*)(qp + d0 + 4);
            short8 v;
            v[0] = (short)f2bf(a.x * SCALE); v[1] = (short)f2bf(a.y * SCALE);
            v[2] = (short)f2bf(a.z * SCALE); v[3] = (short)f2bf(a.w * SCALE);
            v[4] = (short)f2bf(b.x * SCALE); v[5] = (short)f2bf(b.y * SCALE);
            v[6] = (short)f2bf(b.z * SCALE); v[7] = (short)f2bf(b.w * SCALE);
            qf[s] = v;
        }
    }

    __syncthreads();   // sPages visible

    // ---- gather helpers (reg staging) ----
    // K: 1024 units = tok(64) x 16B-bf16 chunk(16); 4 units/thread.
    auto kload = [&](int jb, float4* kr) {
#pragma unroll
        for (int k = 0; k < 4; ++k) {
            const int u = tid + k * 256;
            const int t = u >> 4, h16 = u & 15;
            const int gtok = jb * 64 + t;
            const int page = sPages[gtok >> 4];
            const float* src = kvc + (size_t)page * 32768
                             + (size_t)hkv * 2048 + (gtok & 15) * 128 + h16 * 8;
            kr[2 * k]     = *(const float4*)src;
            kr[2 * k + 1] = *(const float4*)(src + 4);
        }
    };
    auto kstore = [&](const float4* kr) {
#pragma unroll
        for (int k = 0; k < 4; ++k) {
            const int u = tid + k * 256;
            const int t = u >> 4, h16 = u & 15;
            uint4 p;
            p.x = pk2(kr[2*k].x,   kr[2*k].y);
            p.y = pk2(kr[2*k].z,   kr[2*k].w);
            p.z = pk2(kr[2*k+1].x, kr[2*k+1].y);
            p.w = pk2(kr[2*k+1].z, kr[2*k+1].w);
            const uint_t byte = (uint_t)(t * 256) + (((uint_t)(h16 * 16)) ^ ((uint_t)((t & 7) << 4)));
            *(uint4*)(sK + byte) = p;
        }
    };
    // V: thread -> token pair (2tp, 2tp+1), dim chunk c (16 dims).
    auto vload = [&](int jb, float4* vr) {
        const int tp = lane & 31;
        const int c  = w * 2 + (lane >> 5);
        const int gtok = jb * 64 + 2 * tp;
        const int page = sPages[gtok >> 4];
        const float* src = kvc + (size_t)page * 32768 + 16384
                         + (size_t)hkv * 2048 + (gtok & 15) * 128 + c * 16;
#pragma unroll
        for (int i = 0; i < 4; ++i) {
            vr[i]     = ((const float4*)src)[i];
            vr[4 + i] = ((const float4*)(src + 128))[i];
        }
    };
    auto vstore = [&](const float4* vr) {
        const int tp = lane & 31;
        const int c  = w * 2 + (lane >> 5);
#pragma unroll
        for (int dv = 0; dv < 16; ++dv) {
            const int d = c * 16 + dv;
            const uint_t byte = ((uint_t)(d * 128 + 4 * tp)) ^ ((uint_t)((d & 7) << 4));
            const float a = vr[dv >> 2][dv & 3];
            const float b = vr[4 + (dv >> 2)][dv & 3];
            *(uint_t*)(sV + byte) = pk2(a, b);
        }
    };

    f32x4 acc[8];
#pragma unroll
    for (int n2 = 0; n2 < 8; ++n2) acc[n2] = (f32x4){0.f, 0.f, 0.f, 0.f};
    float m_run[4] = {-1e30f, -1e30f, -1e30f, -1e30f};
    float l_run[4] = {0.f, 0.f, 0.f, 0.f};

    float4 kr[8], vr[8];
    // prologue: tile 0 to LDS
    kload(0, kr);
    vload(0, vr);
    kstore(kr);
    vstore(vr);
    __syncthreads();

    for (int jb = 0; jb <= qt; ++jb) {
        const bool pf = (jb < qt);
        if (pf) {            // issue next tile's loads; they fly under compute
            kload(jb + 1, kr);
            vload(jb + 1, vr);
        }

        // ---- S = Q K^T
        f32x4 sacc[4];
#pragma unroll
        for (int n = 0; n < 4; ++n) sacc[n] = (f32x4){0.f, 0.f, 0.f, 0.f};
#pragma unroll
        for (int s = 0; s < 4; ++s) {
#pragma unroll
            for (int n = 0; n < 4; ++n) {
                const int tok = n * 16 + l15;
                const uint_t byte = (uint_t)(tok * 256)
                    + (((uint_t)((s * 32 + lhi * 8) * 2)) ^ ((uint_t)((tok & 7) << 4)));
                short8 kb = *(const short8*)(sK + byte);
                sacc[n] = __builtin_amdgcn_mfma_f32_16x16x32_bf16(qf[s], kb, sacc[n], 0, 0, 0);
            }
        }

        // ---- online softmax
        const bool diag = (jb == qt);
        float pv[4][4];
#pragma unroll
        for (int n = 0; n < 4; ++n)
#pragma unroll
            for (int j = 0; j < 4; ++j) {
                float x = sacc[n][j];
                if (diag) {
                    const int tok = jb * 64 + n * 16 + l15;
                    const int qg  = qt * 64 + w * 16 + lhi * 4 + j;
                    if (tok > qg) x = -1e30f;
                }
                pv[n][j] = x;
            }
#pragma unroll
        for (int j = 0; j < 4; ++j) {
            float mt = fmaxf(fmaxf(pv[0][j], pv[1][j]), fmaxf(pv[2][j], pv[3][j]));
#pragma unroll
            for (int off = 1; off < 16; off <<= 1)
                mt = fmaxf(mt, __shfl_xor(mt, off));
            const float mn = fmaxf(m_run[j], mt);
            const float alpha = __expf(m_run[j] - mn);
            m_run[j] = mn;
            float ls = 0.f;
#pragma unroll
            for (int n = 0; n < 4; ++n) {
                float p = __expf(pv[n][j] - mn);
                pv[n][j] = p;
                ls += p;
            }
#pragma unroll
            for (int off = 1; off < 16; off <<= 1)
                ls += __shfl_xor(ls, off);
            l_run[j] = l_run[j] * alpha + ls;
#pragma unroll
            for (int n2 = 0; n2 < 8; ++n2) acc[n2][j] *= alpha;
        }

        // ---- P -> per-wave LDS (A-fragment relayout)
        char* pb = sP[w];
#pragma unroll
        for (int n = 0; n < 4; ++n)
#pragma unroll
            for (int j = 0; j < 4; ++j) {
                const int r = lhi * 4 + j;
                const uint_t byte = (uint_t)(r * 128)
                    + (((uint_t)((n * 16 + l15) * 2)) ^ ((uint_t)((r & 7) << 4)));
                *(ushort_t*)(pb + byte) = f2bf(pv[n][j]);
            }

        // ---- O += P V
#pragma unroll
        for (int s2 = 0; s2 < 2; ++s2) {
            const uint_t pbyte = (uint_t)(l15 * 128)
                + (((uint_t)((s2 * 32 + lhi * 8) * 2)) ^ ((uint_t)((l15 & 7) << 4)));
            short8 pa = *(const short8*)(pb + pbyte);
#pragma unroll
            for (int n2 = 0; n2 < 8; ++n2) {
                const int dim = n2 * 16 + l15;
                const uint_t vbyte = (uint_t)(dim * 128)
                    + (((uint_t)((s2 * 32 + lhi * 8) * 2)) ^ ((uint_t)((dim & 7) << 4)));
                short8 vbf = *(const short8*)(sV + vbyte);
                acc[n2] = __builtin_amdgcn_mfma_f32_16x16x32_bf16(pa, vbf, acc[n2], 0, 0, 0);
            }
        }

        if (pf) {
            __syncthreads();   // all waves done reading current tiles
            kstore(kr);        // vmcnt wait happens here, loads had whole compute
            vstore(vr);
            __syncthreads();   // new tiles visible
        }
    }

    // ---- epilogue
#pragma unroll
    for (int j = 0; j < 4; ++j) {
        const float inv = 1.0f / l_run[j];
        const int qg = qt * 64 + w * 16 + lhi * 4 + j;
        float* dst = out + (size_t)qg * Q_STRIDE + h * HEAD_DIM;
#pragma unroll
        for (int n2 = 0; n2 < 8; ++n2)
            dst[n2 * 16 + l15] = acc[n2][j] * inv;
    }
}

extern "C" void kernel_launch(void* const* d_in, const int* in_sizes, int n_in,
                              void* d_out, int out_size, void* d_ws, size_t ws_size,
                              hipStream_t stream) {
    const float* q   = (const float*)d_in[0];
    // d_in[1] (k) and d_in[2] (v) are dead under the reference's causal mask.
    const float* kvc = (const float*)d_in[3];
    const int*   bt  = (const int*)d_in[4];
    float* out = (float*)d_out;
    attn_paged_prefill<<<dim3(512), dim3(256), 0, stream>>>(q, kvc, bt, out);
}

// Round 3
// 59.881 us; speedup vs baseline: 2.7947x; 2.7947x over previous
//
#include <hip/hip_runtime.h>
#include <hip/hip_bf16.h>

// GQA paged-prefill attention, MI355X gfx950.
// Causal mask j<=i over concat(past,new) => only first Q_LEN (=1024) gathered
// past tokens are live. Flash-attention over tokens 0..1023 of paged cache.
//
// R3: R1 structure + LDS double-buffer (1 barrier/tile) + register prefetch
// written inline with static indexing ONLY (R2's lambda-pointer staging
// spilled to scratch: 189MB WRITE_SIZE). sPages LDS cache, qt-descending,
// SCALE folded into Q.

#define NUM_HEADS 32
#define HEAD_DIM 128
#define Q_STRIDE 4096
#define SCALE 0.08838834764831845f

typedef short short8 __attribute__((ext_vector_type(8)));
typedef float f32x4 __attribute__((ext_vector_type(4)));
typedef unsigned short ushort_t;
typedef unsigned int uint_t;

__device__ __forceinline__ ushort_t f2bf(float f) {
    uint_t u = __builtin_bit_cast(uint_t, f);
    u += 0x7FFFu + ((u >> 16) & 1u);   // RNE
    return (ushort_t)(u >> 16);
}
__device__ __forceinline__ uint_t pk2(float a, float b) {
    return (uint_t)f2bf(a) | ((uint_t)f2bf(b) << 16);
}

// ---- staging macros: static indices only, no address escapes ----
#define KLOAD(JB)                                                            \
    _Pragma("unroll")                                                        \
    for (int k = 0; k < 4; ++k) {                                            \
        const int page = sPages[(JB) * 4 + k];                               \
        const float* src = kvc + (size_t)page * 32768                       \
                         + (size_t)hkv * 2048 + kt0 * 128 + kh16 * 8;       \
        kr[2 * k]     = *(const float4*)src;                                 \
        kr[2 * k + 1] = *(const float4*)(src + 4);                           \
    }

#define KSTORE(DST)                                                          \
    _Pragma("unroll")                                                        \
    for (int k = 0; k < 4; ++k) {                                            \
        uint4 p;                                                             \
        p.x = pk2(kr[2*k].x,   kr[2*k].y);                                   \
        p.y = pk2(kr[2*k].z,   kr[2*k].w);                                   \
        p.z = pk2(kr[2*k+1].x, kr[2*k+1].y);                                 \
        p.w = pk2(kr[2*k+1].z, kr[2*k+1].w);                                 \
        const uint_t byte = (uint_t)((kt0 + k * 16) * 256)                   \
                          + (((uint_t)(kh16 * 16)) ^ kswz);                  \
        *(uint4*)((DST) + byte) = p;                                         \
    }

#define VLOAD(JB)                                                            \
    {                                                                        \
        const int page = sPages[(JB) * 4 + (vtp >> 3)];                      \
        const float* src = kvc + (size_t)page * 32768 + 16384               \
                         + (size_t)hkv * 2048 + ((2 * vtp) & 15) * 128      \
                         + vc * 16;                                          \
        _Pragma("unroll")                                                    \
        for (int i = 0; i < 4; ++i) {                                        \
            vr[i]     = ((const float4*)src)[i];                             \
            vr[4 + i] = ((const float4*)(src + 128))[i];                     \
        }                                                                    \
    }

#define VSTORE(DST)                                                          \
    _Pragma("unroll")                                                        \
    for (int dv = 0; dv < 16; ++dv) {                                        \
        const int d = vc * 16 + dv;                                          \
        const uint_t byte = ((uint_t)(d * 128 + 4 * vtp))                    \
                          ^ ((uint_t)((d & 7) << 4));                        \
        *(uint_t*)((DST) + byte) = pk2(vr[dv >> 2][dv & 3],                  \
                                       vr[4 + (dv >> 2)][dv & 3]);           \
    }

__launch_bounds__(256)
__global__ void attn_paged_prefill(const float* __restrict__ q,
                                   const float* __restrict__ kvc,
                                   const int* __restrict__ bt,
                                   float* __restrict__ out)
{
    __shared__ __align__(16) char sK[2][64 * 256];    // 2 x 16 KB
    __shared__ __align__(16) char sV[2][128 * 128];   // 2 x 16 KB
    __shared__ __align__(16) char sP[4][2048];        // 8 KB
    __shared__ int sPages[64];

    const int bid = blockIdx.x;
    const int h   = bid & 31;
    const int qt  = 15 - (bid >> 5);   // long blocks first
    const int hkv = h >> 2;
    const int tid  = threadIdx.x;
    const int w    = tid >> 6;
    const int lane = tid & 63;
    const int l15  = lane & 15;
    const int lhi  = lane >> 4;

    if (tid < 64) sPages[tid] = bt[tid];

    // K gather geometry: thread -> (token kt0 + k*16, 16B chunk kh16)
    const int kh16 = tid & 15;
    const int kt0  = tid >> 4;
    const uint_t kswz = (uint_t)((kt0 & 7) << 4);
    // V gather geometry: thread -> token pair (2*vtp, 2*vtp+1), dim chunk vc
    const int vtp = lane & 31;
    const int vc  = w * 2 + (lane >> 5);

    // ---- Q fragments (SCALE folded): wave w owns rows qt*64 + w*16 + l15
    short8 qf[4];
    {
        const int qrow = qt * 64 + w * 16 + l15;
        const float* qp = q + (size_t)qrow * Q_STRIDE + h * HEAD_DIM;
#pragma unroll
        for (int s = 0; s < 4; ++s) {
            const int d0 = s * 32 + lhi * 8;
            float4 a = *(const float4*)(qp + d0);
            float4 b = *(const float4*)(qp + d0 + 4);
            short8 v;
            v[0] = (short)f2bf(a.x * SCALE); v[1] = (short)f2bf(a.y * SCALE);
            v[2] = (short)f2bf(a.z * SCALE); v[3] = (short)f2bf(a.w * SCALE);
            v[4] = (short)f2bf(b.x * SCALE); v[5] = (short)f2bf(b.y * SCALE);
            v[6] = (short)f2bf(b.z * SCALE); v[7] = (short)f2bf(b.w * SCALE);
            qf[s] = v;
        }
    }

    f32x4 acc[8];
#pragma unroll
    for (int n2 = 0; n2 < 8; ++n2) acc[n2] = (f32x4){0.f, 0.f, 0.f, 0.f};
    float m_run[4] = {-1e30f, -1e30f, -1e30f, -1e30f};
    float l_run[4] = {0.f, 0.f, 0.f, 0.f};

    __syncthreads();   // sPages visible

    float4 kr[8], vr[8];
    // prologue: tile 0 -> buf 0
    KLOAD(0)
    VLOAD(0)
    KSTORE(sK[0])
    VSTORE(sV[0])
    __syncthreads();

    for (int jb = 0; jb <= qt; ++jb) {
        const int cur = jb & 1;
        char* kbuf = sK[cur];
        char* vbuf = sV[cur];
        const bool pf = (jb < qt);
        if (pf) {            // issue next tile's loads; fly under compute
            KLOAD(jb + 1)
            VLOAD(jb + 1)
        }

        // ---- S = Q K^T
        f32x4 sacc[4];
#pragma unroll
        for (int n = 0; n < 4; ++n) sacc[n] = (f32x4){0.f, 0.f, 0.f, 0.f};
#pragma unroll
        for (int s = 0; s < 4; ++s) {
#pragma unroll
            for (int n = 0; n < 4; ++n) {
                const int tok = n * 16 + l15;
                const uint_t byte = (uint_t)(tok * 256)
                    + (((uint_t)((s * 32 + lhi * 8) * 2)) ^ ((uint_t)((tok & 7) << 4)));
                short8 kb = *(const short8*)(kbuf + byte);
                sacc[n] = __builtin_amdgcn_mfma_f32_16x16x32_bf16(qf[s], kb, sacc[n], 0, 0, 0);
            }
        }

        // ---- online softmax
        const bool diag = (jb == qt);
        float pv[4][4];
#pragma unroll
        for (int n = 0; n < 4; ++n)
#pragma unroll
            for (int j = 0; j < 4; ++j) {
                float x = sacc[n][j];
                if (diag) {
                    const int tok = jb * 64 + n * 16 + l15;
                    const int qg  = qt * 64 + w * 16 + lhi * 4 + j;
                    if (tok > qg) x = -1e30f;
                }
                pv[n][j] = x;
            }
#pragma unroll
        for (int j = 0; j < 4; ++j) {
            float mt = fmaxf(fmaxf(pv[0][j], pv[1][j]), fmaxf(pv[2][j], pv[3][j]));
#pragma unroll
            for (int off = 1; off < 16; off <<= 1)
                mt = fmaxf(mt, __shfl_xor(mt, off));
            const float mn = fmaxf(m_run[j], mt);
            const float alpha = __expf(m_run[j] - mn);
            m_run[j] = mn;
            float ls = 0.f;
#pragma unroll
            for (int n = 0; n < 4; ++n) {
                float p = __expf(pv[n][j] - mn);
                pv[n][j] = p;
                ls += p;
            }
#pragma unroll
            for (int off = 1; off < 16; off <<= 1)
                ls += __shfl_xor(ls, off);
            l_run[j] = l_run[j] * alpha + ls;
#pragma unroll
            for (int n2 = 0; n2 < 8; ++n2) acc[n2][j] *= alpha;
        }

        // ---- P -> per-wave LDS (A-fragment relayout)
        char* pb = sP[w];
#pragma unroll
        for (int n = 0; n < 4; ++n)
#pragma unroll
            for (int j = 0; j < 4; ++j) {
                const int r = lhi * 4 + j;
                const uint_t byte = (uint_t)(r * 128)
                    + (((uint_t)((n * 16 + l15) * 2)) ^ ((uint_t)((r & 7) << 4)));
                *(ushort_t*)(pb + byte) = f2bf(pv[n][j]);
            }

        // ---- O += P V
#pragma unroll
        for (int s2 = 0; s2 < 2; ++s2) {
            const uint_t pbyte = (uint_t)(l15 * 128)
                + (((uint_t)((s2 * 32 + lhi * 8) * 2)) ^ ((uint_t)((l15 & 7) << 4)));
            short8 pa = *(const short8*)(pb + pbyte);
#pragma unroll
            for (int n2 = 0; n2 < 8; ++n2) {
                const int dim = n2 * 16 + l15;
                const uint_t vbyte = (uint_t)(dim * 128)
                    + (((uint_t)((s2 * 32 + lhi * 8) * 2)) ^ ((uint_t)((dim & 7) << 4)));
                short8 vbf = *(const short8*)(vbuf + vbyte);
                acc[n2] = __builtin_amdgcn_mfma_f32_16x16x32_bf16(pa, vbf, acc[n2], 0, 0, 0);
            }
        }

        if (pf) {   // store next tile into the other buffer, then one barrier
            char* kn = sK[cur ^ 1];
            char* vn = sV[cur ^ 1];
            KSTORE(kn)
            VSTORE(vn)
            __syncthreads();
        }
    }

    // ---- epilogue
#pragma unroll
    for (int j = 0; j < 4; ++j) {
        const float inv = 1.0f / l_run[j];
        const int qg = qt * 64 + w * 16 + lhi * 4 + j;
        float* dst = out + (size_t)qg * Q_STRIDE + h * HEAD_DIM;
#pragma unroll
        for (int n2 = 0; n2 < 8; ++n2)
            dst[n2 * 16 + l15] = acc[n2][j] * inv;
    }
}

extern "C" void kernel_launch(void* const* d_in, const int* in_sizes, int n_in,
                              void* d_out, int out_size, void* d_ws, size_t ws_size,
                              hipStream_t stream) {
    const float* q   = (const float*)d_in[0];
    // d_in[1] (k) and d_in[2] (v) are dead under the reference's causal mask.
    const float* kvc = (const float*)d_in[3];
    const int*   bt  = (const int*)d_in[4];
    float* out = (float*)d_out;
    attn_paged_prefill<<<dim3(512), dim3(256), 0, stream>>>(q, kvc, bt, out);
}